// Round 1
// baseline (3319.963 us; speedup 1.0000x reference)
//
#include <hip/hip_runtime.h>
#include <hip/hip_bf16.h>
#include <math.h>

// Problem constants (fixed by the reference)
#define NN 50000
#define EE 400000
#define TT 4
#define DIN 64
#define DD 128
#define BB 64
#define STEPS 8
#define KAGG 544   // 512 (T*D) + 4 (per-type edge counts for b_msg) + 28 zero pad -> 17*32

__device__ inline float toF(float x) { return x; }
__device__ inline float toF(__hip_bfloat16 x) { return __bfloat162float(x); }

// ---------------------------------------------------------------- init h (zero-pad 64->128)
__global__ void k_init_h(const float* __restrict__ feat, float* __restrict__ h,
                         float* __restrict__ h1) {
    int idx = blockIdx.x * blockDim.x + threadIdx.x;
    if (idx >= NN * DD) return;
    int v = idx >> 7, d = idx & 127;
    float val = (d < DIN) ? feat[v * DIN + d] : 0.0f;
    h[idx] = val;
    h1[idx] = val;
}

__global__ void k_zero_i32(int* __restrict__ p, int n) {
    int idx = blockIdx.x * blockDim.x + threadIdx.x;
    if (idx < n) p[idx] = 0;
}
__global__ void k_zero_f32(float* __restrict__ p, int n) {
    int idx = blockIdx.x * blockDim.x + threadIdx.x;
    if (idx < n) p[idx] = 0.0f;
}

// ---------------------------------------------------------------- CSR build (by dst)
__global__ void k_hist(const int* __restrict__ dst, int* __restrict__ deg) {
    int e = blockIdx.x * blockDim.x + threadIdx.x;
    if (e < EE) atomicAdd(&deg[dst[e]], 1);
}

__global__ __launch_bounds__(1024) void k_scan(const int* __restrict__ deg,
                                               int* __restrict__ off,
                                               int* __restrict__ cursor) {
    __shared__ int sums[1024];
    int tid = threadIdx.x;
    const int CH = (NN + 1023) / 1024;  // 49
    int start = tid * CH;
    int end = start + CH;
    if (start > NN) start = NN;
    if (end > NN) end = NN;
    int s = 0;
    for (int i = start; i < end; ++i) s += deg[i];
    sums[tid] = s;
    __syncthreads();
    for (int dlt = 1; dlt < 1024; dlt <<= 1) {
        int v = (tid >= dlt) ? sums[tid - dlt] : 0;
        __syncthreads();
        sums[tid] += v;
        __syncthreads();
    }
    int run = sums[tid] - s;  // exclusive base
    for (int i = start; i < end; ++i) {
        off[i] = run;
        cursor[i] = run;
        run += deg[i];
    }
    if (end == NN && start < NN) off[NN] = run;  // == EE
}

__global__ void k_fill(const int* __restrict__ dst, int* __restrict__ cursor,
                       int* __restrict__ csr_e) {
    int e = blockIdx.x * blockDim.x + threadIdx.x;
    if (e < EE) {
        int pos = atomicAdd(&cursor[dst[e]], 1);
        csr_e[pos] = e;
    }
}

// ---------------------------------------------------------------- W_cat build: [544][128]
// rows 0..511: W_msg[t][d][:], row k = t*128+d ; rows 512..515: b_msg[t][:] ; rest 0
__global__ void k_wcat(const float* __restrict__ Wm, const float* __restrict__ bm,
                       float* __restrict__ Wc) {
    int idx = blockIdx.x * blockDim.x + threadIdx.x;
    if (idx >= KAGG * DD) return;
    int k = idx >> 7, e = idx & 127;
    float v;
    if (k < 512) {
        int t = k >> 7, d = k & 127;
        v = Wm[(t << 14) + (d << 7) + e];
    } else if (k < 516) {
        v = bm[((k - 512) << 7) + e];
    } else {
        v = 0.0f;
    }
    Wc[idx] = v;
}

// ---------------------------------------------------------------- per-type aggregation
// one wave (64 lanes) per node; lane owns dims (lane, lane+64)
__global__ __launch_bounds__(256) void k_agg(const float* __restrict__ h,
                                             const int* __restrict__ off,
                                             const int* __restrict__ csr_e,
                                             const int* __restrict__ src,
                                             const int* __restrict__ etype,
                                             __hip_bfloat16* __restrict__ g) {
    int wave = (blockIdx.x * blockDim.x + threadIdx.x) >> 6;
    int lane = threadIdx.x & 63;
    if (wave >= NN) return;
    int v = wave;
    int beg = off[v], end = off[v + 1];
    float acc[TT][2] = {};
    int cnt[TT] = {};
    for (int p = beg; p < end; ++p) {
        int e = csr_e[p];
        int s = src[e];
        int t = etype[e];
        float v0 = h[(size_t)s * DD + lane];
        float v1 = h[(size_t)s * DD + 64 + lane];
#pragma unroll
        for (int q = 0; q < TT; ++q) {
            bool m = (t == q);
            acc[q][0] += m ? v0 : 0.0f;
            acc[q][1] += m ? v1 : 0.0f;
            cnt[q] += m ? 1 : 0;
        }
    }
    __hip_bfloat16* row = g + (size_t)v * KAGG;
#pragma unroll
    for (int q = 0; q < TT; ++q) {
        row[q * DD + lane] = __float2bfloat16(acc[q][0]);
        row[q * DD + 64 + lane] = __float2bfloat16(acc[q][1]);
    }
    if (lane < 32) {
        float cv = 0.0f;
        if (lane == 0) cv = (float)cnt[0];
        else if (lane == 1) cv = (float)cnt[1];
        else if (lane == 2) cv = (float)cnt[2];
        else if (lane == 3) cv = (float)cnt[3];
        row[512 + lane] = __float2bfloat16(cv);
    }
}

// ---------------------------------------------------------------- generic tiled GEMM
// C[M x (gridDim.y*128)] = A[M x K] * W[K x ldw] (+bias), C stored bf16
// tile: 64 rows x 128 cols, 256 threads, 32 outputs/thread
template <typename TA>
__global__ __launch_bounds__(256) void gemm_bias(const TA* __restrict__ A, int lda, int M,
                                                 int K, const float* __restrict__ W, int ldw,
                                                 const float* __restrict__ bias,
                                                 __hip_bfloat16* __restrict__ C, int ldc) {
    const int BM = 64, BN = 128, BK = 32;
    __shared__ float As[BM][BK + 1];
    __shared__ float Ws[BK][BN];
    int tid = threadIdx.x;
    int row0 = blockIdx.x * BM;
    int col0 = blockIdx.y * BN;
    int tx = tid & 15, ty = tid >> 4;
    float acc[4][8] = {};

    for (int k0 = 0; k0 < K; k0 += BK) {
        // stage A: 64x32, 8 elems/thread
        {
            int r = tid >> 2;
            int kb = (tid & 3) * 8;
            int grow = row0 + r;
            if (grow >= M) grow = M - 1;
            const TA* ap = A + (size_t)grow * lda + k0 + kb;
#pragma unroll
            for (int i = 0; i < 8; ++i) As[r][kb + i] = toF(ap[i]);
        }
        // stage W: 32x128, 16 elems/thread
        {
            int kr = tid >> 3;
            int cb = (tid & 7) * 16;
            const float* wp = W + (size_t)(k0 + kr) * ldw + col0 + cb;
#pragma unroll
            for (int i = 0; i < 16; ++i) Ws[kr][cb + i] = wp[i];
        }
        __syncthreads();
#pragma unroll
        for (int kk = 0; kk < BK; ++kk) {
            float av[4], wv[8];
#pragma unroll
            for (int ir = 0; ir < 4; ++ir) av[ir] = As[ty * 4 + ir][kk];
#pragma unroll
            for (int jc = 0; jc < 8; ++jc) wv[jc] = Ws[kk][tx + 16 * jc];
#pragma unroll
            for (int ir = 0; ir < 4; ++ir)
#pragma unroll
                for (int jc = 0; jc < 8; ++jc) acc[ir][jc] += av[ir] * wv[jc];
        }
        __syncthreads();
    }
#pragma unroll
    for (int ir = 0; ir < 4; ++ir) {
        int r = row0 + ty * 4 + ir;
        if (r >= M) continue;
#pragma unroll
        for (int jc = 0; jc < 8; ++jc) {
            int c = col0 + tx + 16 * jc;
            float val = acc[ir][jc] + (bias ? bias[c] : 0.0f);
            C[(size_t)r * ldc + c] = __float2bfloat16(val);
        }
    }
}

// ---------------------------------------------------------------- GRU gates (elementwise)
__global__ void k_gates(const __hip_bfloat16* __restrict__ gi,
                        const __hip_bfloat16* __restrict__ gh,
                        const float* __restrict__ h, float* __restrict__ hn) {
    int idx = blockIdx.x * blockDim.x + threadIdx.x;
    if (idx >= NN * DD) return;
    int v = idx >> 7, d = idx & 127;
    const __hip_bfloat16* gir = gi + (size_t)v * 384;
    const __hip_bfloat16* ghr = gh + (size_t)v * 384;
    float i_r = toF(gir[d]), i_z = toF(gir[d + 128]), i_n = toF(gir[d + 256]);
    float h_r = toF(ghr[d]), h_z = toF(ghr[d + 128]), h_n = toF(ghr[d + 256]);
    float hv = h[idx];
    float r = 1.0f / (1.0f + __expf(-(i_r + h_r)));
    float z = 1.0f / (1.0f + __expf(-(i_z + h_z)));
    float n = tanhf(i_n + r * h_n);
    hn[idx] = (1.0f - z) * n + z * hv;
}

// ---------------------------------------------------------------- readout (n2g is sorted)
__global__ __launch_bounds__(128) void k_readout(const float* __restrict__ h,
                                                 const float* __restrict__ h1,
                                                 const int* __restrict__ n2g,
                                                 float* __restrict__ feats) {
    const int CH = 384;
    int d = threadIdx.x;
    int v0 = blockIdx.x * CH;
    if (v0 >= NN) return;
    int v1 = v0 + CH;
    if (v1 > NN) v1 = NN;
    float sum = 0.0f;
    int cur = n2g[v0];
    for (int v = v0; v < v1; ++v) {
        int gph = n2g[v];
        if (gph != cur) {
            atomicAdd(&feats[cur * DD + d], sum);
            sum = 0.0f;
            cur = gph;
        }
        sum += h[(size_t)v * DD + d] + h1[(size_t)v * DD + d];
    }
    atomicAdd(&feats[cur * DD + d], sum);
}

// ---------------------------------------------------------------- classifier
__global__ void k_cls(const float* __restrict__ feats, const float* __restrict__ Wc,
                      const float* __restrict__ bc, float* __restrict__ out) {
    int t = threadIdx.x;
    if (t >= BB * 2) return;
    int b = t >> 1, c = t & 1;
    float s = bc[c];
    for (int d = 0; d < DD; ++d) s += feats[b * DD + d] * Wc[d * 2 + c];
    out[t] = s;
}

// ================================================================ launcher
extern "C" void kernel_launch(void* const* d_in, const int* in_sizes, int n_in, void* d_out,
                              int out_size, void* d_ws, size_t ws_size, hipStream_t stream) {
    const float* features = (const float*)d_in[0];
    const int* src = (const int*)d_in[1];
    const int* dst = (const int*)d_in[2];
    const int* etype = (const int*)d_in[3];
    const int* n2g = (const int*)d_in[4];
    const float* W_msg = (const float*)d_in[5];
    const float* b_msg = (const float*)d_in[6];
    const float* w_ih = (const float*)d_in[7];
    const float* b_ih = (const float*)d_in[8];
    const float* w_hh = (const float*)d_in[9];
    const float* b_hh = (const float*)d_in[10];
    const float* W_cls = (const float*)d_in[11];
    const float* b_cls = (const float*)d_in[12];
    float* out = (float*)d_out;

    char* ws = (char*)d_ws;
    size_t o = 0;
    auto alloc = [&](size_t bytes) {
        o = (o + 255) & ~(size_t)255;
        void* p = ws + o;
        o += bytes;
        return p;
    };
    int* deg = (int*)alloc(sizeof(int) * NN);
    int* off = (int*)alloc(sizeof(int) * (NN + 1));
    int* cursor = (int*)alloc(sizeof(int) * NN);
    int* csr_e = (int*)alloc(sizeof(int) * EE);
    float* Wcat = (float*)alloc(sizeof(float) * KAGG * DD);
    float* h0 = (float*)alloc(sizeof(float) * NN * DD);
    float* h1p = (float*)alloc(sizeof(float) * NN * DD);
    float* hini = (float*)alloc(sizeof(float) * NN * DD);
    __hip_bfloat16* g = (__hip_bfloat16*)alloc(sizeof(__hip_bfloat16) * (size_t)NN * KAGG);
    __hip_bfloat16* abuf = (__hip_bfloat16*)alloc(sizeof(__hip_bfloat16) * (size_t)NN * DD);
    __hip_bfloat16* ghb = (__hip_bfloat16*)alloc(sizeof(__hip_bfloat16) * (size_t)NN * 384);
    float* feats = (float*)alloc(sizeof(float) * BB * DD);
    // gi aliases g's buffer: g (54.4MB) is dead once 'a' is computed; gi needs 38.4MB
    __hip_bfloat16* gib = g;

    // setup
    k_init_h<<<(NN * DD + 255) / 256, 256, 0, stream>>>(features, h0, hini);
    k_zero_i32<<<(NN + 255) / 256, 256, 0, stream>>>(deg, NN);
    k_zero_f32<<<(BB * DD + 255) / 256, 256, 0, stream>>>(feats, BB * DD);
    k_hist<<<(EE + 255) / 256, 256, 0, stream>>>(dst, deg);
    k_scan<<<1, 1024, 0, stream>>>(deg, off, cursor);
    k_fill<<<(EE + 255) / 256, 256, 0, stream>>>(dst, cursor, csr_e);
    k_wcat<<<(KAGG * DD + 255) / 256, 256, 0, stream>>>(W_msg, b_msg, Wcat);

    const int MT = (NN + 63) / 64;  // 782 row tiles
    float* hc = h0;
    float* hx = h1p;
    for (int s = 0; s < STEPS; ++s) {
        k_agg<<<(NN * 64 + 255) / 256, 256, 0, stream>>>(hc, off, csr_e, src, etype, g);
        gemm_bias<__hip_bfloat16><<<dim3(MT, 1), 256, 0, stream>>>(
            g, KAGG, NN, KAGG, Wcat, DD, nullptr, abuf, DD);
        gemm_bias<__hip_bfloat16><<<dim3(MT, 3), 256, 0, stream>>>(
            abuf, DD, NN, DD, w_ih, 384, b_ih, gib, 384);
        gemm_bias<float><<<dim3(MT, 3), 256, 0, stream>>>(
            hc, DD, NN, DD, w_hh, 384, b_hh, ghb, 384);
        k_gates<<<(NN * DD + 255) / 256, 256, 0, stream>>>(gib, ghb, hc, hx);
        float* tmp = hc;
        hc = hx;
        hx = tmp;
    }
    k_readout<<<(NN + 383) / 384, 128, 0, stream>>>(hc, hini, n2g, feats);
    k_cls<<<1, 128, 0, stream>>>(feats, W_cls, b_cls, out);
}

// Round 2
// 1573.787 us; speedup vs baseline: 2.1095x; 2.1095x over previous
//
#include <hip/hip_runtime.h>
#include <hip/hip_bf16.h>
#include <math.h>

// Problem constants (fixed by the reference)
#define NN 50000
#define EE 400000
#define TT 4
#define DIN 64
#define DD 128
#define BB 64
#define STEPS 8
#define KAGG 544    // 512 (T*D) + 4 (per-type counts for b_msg) + 28 pad -> 17*32
#define KGATES 256  // [a | h]
#define NGATES 512  // [r_sum, z_sum, i_n, h_n]

typedef __attribute__((ext_vector_type(8))) short bf16x8;
typedef __attribute__((ext_vector_type(4))) float f32x4;
typedef __attribute__((address_space(3))) void lds_void;
typedef __attribute__((address_space(1))) void glob_void;

__device__ inline float bf2f(__hip_bfloat16 x) { return __bfloat162float(x); }

// ---------------------------------------------------------------- init h (zero-pad 64->128)
__global__ void k_init_h(const float* __restrict__ feat, float* __restrict__ h,
                         float* __restrict__ h1, __hip_bfloat16* __restrict__ hb) {
    int idx = blockIdx.x * blockDim.x + threadIdx.x;
    if (idx >= NN * DD) return;
    int v = idx >> 7, d = idx & 127;
    float val = (d < DIN) ? feat[v * DIN + d] : 0.0f;
    h[idx] = val;
    h1[idx] = val;
    hb[idx] = __float2bfloat16(val);
}

__global__ void k_zero_i32(int* __restrict__ p, int n) {
    int idx = blockIdx.x * blockDim.x + threadIdx.x;
    if (idx < n) p[idx] = 0;
}
__global__ void k_zero_f32(float* __restrict__ p, int n) {
    int idx = blockIdx.x * blockDim.x + threadIdx.x;
    if (idx < n) p[idx] = 0.0f;
}

// ---------------------------------------------------------------- CSR build (by dst)
__global__ void k_hist(const int* __restrict__ dst, int* __restrict__ deg) {
    int e = blockIdx.x * blockDim.x + threadIdx.x;
    if (e < EE) atomicAdd(&deg[dst[e]], 1);
}

__global__ __launch_bounds__(1024) void k_scan(const int* __restrict__ deg,
                                               int* __restrict__ off,
                                               int* __restrict__ cursor) {
    __shared__ int sums[1024];
    int tid = threadIdx.x;
    const int CH = (NN + 1023) / 1024;  // 49
    int start = tid * CH;
    int end = start + CH;
    if (start > NN) start = NN;
    if (end > NN) end = NN;
    int s = 0;
    for (int i = start; i < end; ++i) s += deg[i];
    sums[tid] = s;
    __syncthreads();
    for (int dlt = 1; dlt < 1024; dlt <<= 1) {
        int v = (tid >= dlt) ? sums[tid - dlt] : 0;
        __syncthreads();
        sums[tid] += v;
        __syncthreads();
    }
    int run = sums[tid] - s;  // exclusive base
    for (int i = start; i < end; ++i) {
        off[i] = run;
        cursor[i] = run;
        run += deg[i];
    }
    if (end == NN && start < NN) off[NN] = run;  // == EE
}

// pack src+etype so the agg inner loop does ONE indexed load per edge
__global__ void k_fill(const int* __restrict__ dst, const int* __restrict__ src,
                       const int* __restrict__ etype, int* __restrict__ cursor,
                       int* __restrict__ csr_dat) {
    int e = blockIdx.x * blockDim.x + threadIdx.x;
    if (e < EE) {
        int pos = atomicAdd(&cursor[dst[e]], 1);
        csr_dat[pos] = (src[e] << 2) | etype[e];
    }
}

// ---------------------------------------------------------------- weight prep (once/call)
// WcatT [128 n][544 k] bf16 : k<512 -> W_msg[t=k>>7][d=k&127][n]; k 512..515 -> b_msg[t][n]
// WgT   [512 n][256 k] bf16 : k<128 (a-part, d=k):   n<384 -> w_ih[d][n] else 0
//                             k>=128 (h-part, d=k-128): n<256 -> w_hh[d][n];
//                                                       n<384 -> 0; else w_hh[d][n-128]
// bias512: n<256 -> b_ih[n]+b_hh[n]; n<384 -> b_ih[n]; else b_hh[n-128]
__global__ void k_prep_w(const float* __restrict__ Wm, const float* __restrict__ bm,
                         const float* __restrict__ wih, const float* __restrict__ bih,
                         const float* __restrict__ whh, const float* __restrict__ bhh,
                         __hip_bfloat16* __restrict__ WcatT, __hip_bfloat16* __restrict__ WgT,
                         float* __restrict__ bias512) {
    int idx = blockIdx.x * blockDim.x + threadIdx.x;
    if (idx < 128 * KAGG) {
        int n = idx / KAGG, k = idx % KAGG;
        float v = 0.0f;
        if (k < 512) {
            int t = k >> 7, d = k & 127;
            v = Wm[(t << 14) + (d << 7) + n];
        } else if (k < 516) {
            v = bm[((k - 512) << 7) + n];
        }
        WcatT[idx] = __float2bfloat16(v);
    }
    int j = idx - 128 * KAGG;
    if (j >= 0 && j < NGATES * KGATES) {
        int n = j >> 8, k = j & 255;
        float v;
        if (k < 128) {
            v = (n < 384) ? wih[k * 384 + n] : 0.0f;
        } else {
            int d = k - 128;
            v = (n < 256) ? whh[d * 384 + n] : ((n < 384) ? 0.0f : whh[d * 384 + n - 128]);
        }
        WgT[j] = __float2bfloat16(v);
    }
    int b = idx - (128 * KAGG + NGATES * KGATES);
    if (b >= 0 && b < NGATES) {
        float v;
        if (b < 256) v = bih[b] + bhh[b];
        else if (b < 384) v = bih[b];
        else v = bhh[b - 128];
        bias512[b] = v;
    }
}

// ---------------------------------------------------------------- per-type aggregation
// one wave per node; lane owns dims (2*lane, 2*lane+1) via bf162 loads
__global__ __launch_bounds__(256) void k_agg(const __hip_bfloat16* __restrict__ hb,
                                             const int* __restrict__ off,
                                             const int* __restrict__ csr_dat,
                                             __hip_bfloat16* __restrict__ g) {
    int node = (blockIdx.x * blockDim.x + threadIdx.x) >> 6;
    int lane = threadIdx.x & 63;
    if (node >= NN) return;
    int beg = off[node], end = off[node + 1];
    const __hip_bfloat162* hb2 = (const __hip_bfloat162*)hb;
    float2 acc[TT] = {};
    int cnt[TT] = {};
    for (int p = beg; p < end; ++p) {
        int dat = csr_dat[p];
        int s = dat >> 2;
        int t = dat & 3;
        __hip_bfloat162 v = hb2[(size_t)s * 64 + lane];
        float vx = bf2f(v.x), vy = bf2f(v.y);
#pragma unroll
        for (int q = 0; q < TT; ++q) {
            bool m = (t == q);
            acc[q].x += m ? vx : 0.0f;
            acc[q].y += m ? vy : 0.0f;
            cnt[q] += m ? 1 : 0;
        }
    }
    __hip_bfloat162* grow = (__hip_bfloat162*)(g + (size_t)node * KAGG);
#pragma unroll
    for (int q = 0; q < TT; ++q) {
        __hip_bfloat162 o;
        o.x = __float2bfloat16(acc[q].x);
        o.y = __float2bfloat16(acc[q].y);
        grow[q * 64 + lane] = o;
    }
    if (lane < 16) {  // cols 512..543: counts then zero pad
        float c0 = (2 * lane < TT) ? (float)cnt[2 * lane] : 0.0f;
        float c1 = (2 * lane + 1 < TT) ? (float)cnt[2 * lane + 1] : 0.0f;
        __hip_bfloat162 o;
        o.x = __float2bfloat16(c0);
        o.y = __float2bfloat16(c1);
        grow[256 + lane] = o;
    }
}

// ---------------------------------------------------------------- MFMA GEMM
// C[M x ...] = A[M x K] * BT^T (+bias), 128x128 tile, BK=32, 4 waves 2x2, bf16 out.
// DUAL: A = [A0 | A1] split at k=128 (both lda).
// BT is [Ncols][K] row-major (pre-transposed weights).
template <bool DUAL>
__global__ __launch_bounds__(256) void gemm_mfma(
    const __hip_bfloat16* __restrict__ A0, const __hip_bfloat16* __restrict__ A1, int lda,
    int K, const __hip_bfloat16* __restrict__ BT, int ldb, const float* __restrict__ bias,
    __hip_bfloat16* __restrict__ C, int ldc) {
    __shared__ short As[128 * 32];
    __shared__ short Bs[128 * 32];
    const int tid = threadIdx.x;
    const int lane = tid & 63;
    const int wave = tid >> 6;
    const int row0 = blockIdx.x * 128;
    const int col0 = blockIdx.y * 128;
    const int wm = (wave & 1) * 64;
    const int wn = (wave >> 1) * 64;
    const int quad = lane >> 4;
    const int m16 = lane & 15;

    f32x4 acc[4][4];
#pragma unroll
    for (int t = 0; t < 4; ++t)
#pragma unroll
        for (int u = 0; u < 4; ++u) acc[t][u] = (f32x4){0.f, 0.f, 0.f, 0.f};

    for (int k0 = 0; k0 < K; k0 += 32) {
#pragma unroll
        for (int i = 0; i < 2; ++i) {
            int s = tid + i * 256;  // slot: 512 slots of 16B per 128x32 tile
            int srow = s >> 2;
            int kp = (s & 3) * 8;
            // A: row0+srow, k0+kp
            int grow = row0 + srow;
            if (grow >= NN) grow = NN - 1;
            const __hip_bfloat16* ga;
            if (DUAL) {
                // k0 is 32-aligned and split is at 128 -> branch is k0-uniform
                ga = (k0 < 128) ? (A0 + (size_t)grow * lda + k0 + kp)
                                : (A1 + (size_t)grow * lda + (k0 - 128) + kp);
            } else {
                ga = A0 + (size_t)grow * lda + k0 + kp;
            }
            __builtin_amdgcn_global_load_lds((const glob_void*)ga,
                                             (lds_void*)&As[(wave * 64 + i * 256) * 8], 16, 0, 0);
            // B: row (col0+srow) of BT
            const __hip_bfloat16* gb = BT + (size_t)(col0 + srow) * ldb + k0 + kp;
            __builtin_amdgcn_global_load_lds((const glob_void*)gb,
                                             (lds_void*)&Bs[(wave * 64 + i * 256) * 8], 16, 0, 0);
        }
        __syncthreads();
        bf16x8 af[4], bfr[4];
#pragma unroll
        for (int t = 0; t < 4; ++t) af[t] = *(bf16x8*)&As[(wm + t * 16 + m16) * 32 + quad * 8];
#pragma unroll
        for (int u = 0; u < 4; ++u) bfr[u] = *(bf16x8*)&Bs[(wn + u * 16 + m16) * 32 + quad * 8];
#pragma unroll
        for (int t = 0; t < 4; ++t)
#pragma unroll
            for (int u = 0; u < 4; ++u)
                acc[t][u] = __builtin_amdgcn_mfma_f32_16x16x32_bf16(af[t], bfr[u], acc[t][u], 0, 0, 0);
        __syncthreads();
    }
#pragma unroll
    for (int u = 0; u < 4; ++u) {
        int col = col0 + wn + u * 16 + m16;
        float bv = bias ? bias[col] : 0.0f;
#pragma unroll
        for (int t = 0; t < 4; ++t) {
            int rbase = row0 + wm + t * 16 + quad * 4;
#pragma unroll
            for (int r = 0; r < 4; ++r) {
                int row = rbase + r;
                if (row < NN) C[(size_t)row * ldc + col] = __float2bfloat16(acc[t][u][r] + bv);
            }
        }
    }
}

// ---------------------------------------------------------------- GRU gates (elementwise)
// gates_pre cols: [0:128)=i_r+h_r, [128:256)=i_z+h_z, [256:384)=i_n, [384:512)=h_n
__global__ __launch_bounds__(256) void k_gates(const __hip_bfloat16* __restrict__ gp,
                                               const float* __restrict__ h,
                                               float* __restrict__ hn,
                                               __hip_bfloat16* __restrict__ hbn) {
    int idx = blockIdx.x * blockDim.x + threadIdx.x;
    if (idx >= NN * 64) return;
    int v = idx >> 6, d2 = idx & 63;
    const __hip_bfloat162* row = (const __hip_bfloat162*)(gp + (size_t)v * NGATES);
    __hip_bfloat162 rs2 = row[d2];
    __hip_bfloat162 zs2 = row[64 + d2];
    __hip_bfloat162 in2 = row[128 + d2];
    __hip_bfloat162 hn2 = row[192 + d2];
    float2 hv = ((const float2*)h)[(size_t)v * 64 + d2];
    float r0 = 1.0f / (1.0f + __expf(-bf2f(rs2.x)));
    float r1 = 1.0f / (1.0f + __expf(-bf2f(rs2.y)));
    float z0 = 1.0f / (1.0f + __expf(-bf2f(zs2.x)));
    float z1 = 1.0f / (1.0f + __expf(-bf2f(zs2.y)));
    float n0 = tanhf(bf2f(in2.x) + r0 * bf2f(hn2.x));
    float n1 = tanhf(bf2f(in2.y) + r1 * bf2f(hn2.y));
    float o0 = (1.0f - z0) * n0 + z0 * hv.x;
    float o1 = (1.0f - z1) * n1 + z1 * hv.y;
    float2 o;
    o.x = o0;
    o.y = o1;
    ((float2*)hn)[(size_t)v * 64 + d2] = o;
    __hip_bfloat162 ob;
    ob.x = __float2bfloat16(o0);
    ob.y = __float2bfloat16(o1);
    ((__hip_bfloat162*)hbn)[(size_t)v * 64 + d2] = ob;
}

// ---------------------------------------------------------------- readout (n2g is sorted)
__global__ __launch_bounds__(128) void k_readout(const float* __restrict__ h,
                                                 const float* __restrict__ h1,
                                                 const int* __restrict__ n2g,
                                                 float* __restrict__ feats) {
    const int CH = 384;
    int d = threadIdx.x;
    int v0 = blockIdx.x * CH;
    if (v0 >= NN) return;
    int v1 = v0 + CH;
    if (v1 > NN) v1 = NN;
    float sum = 0.0f;
    int cur = n2g[v0];
    for (int v = v0; v < v1; ++v) {
        int gph = n2g[v];
        if (gph != cur) {
            atomicAdd(&feats[cur * DD + d], sum);
            sum = 0.0f;
            cur = gph;
        }
        sum += h[(size_t)v * DD + d] + h1[(size_t)v * DD + d];
    }
    atomicAdd(&feats[cur * DD + d], sum);
}

// ---------------------------------------------------------------- classifier
__global__ void k_cls(const float* __restrict__ feats, const float* __restrict__ Wc,
                      const float* __restrict__ bc, float* __restrict__ out) {
    int t = threadIdx.x;
    if (t >= BB * 2) return;
    int b = t >> 1, c = t & 1;
    float s = bc[c];
    for (int d = 0; d < DD; ++d) s += feats[b * DD + d] * Wc[d * 2 + c];
    out[t] = s;
}

// ================================================================ launcher
extern "C" void kernel_launch(void* const* d_in, const int* in_sizes, int n_in, void* d_out,
                              int out_size, void* d_ws, size_t ws_size, hipStream_t stream) {
    const float* features = (const float*)d_in[0];
    const int* src = (const int*)d_in[1];
    const int* dst = (const int*)d_in[2];
    const int* etype = (const int*)d_in[3];
    const int* n2g = (const int*)d_in[4];
    const float* W_msg = (const float*)d_in[5];
    const float* b_msg = (const float*)d_in[6];
    const float* w_ih = (const float*)d_in[7];
    const float* b_ih = (const float*)d_in[8];
    const float* w_hh = (const float*)d_in[9];
    const float* b_hh = (const float*)d_in[10];
    const float* W_cls = (const float*)d_in[11];
    const float* b_cls = (const float*)d_in[12];
    float* out = (float*)d_out;

    char* ws = (char*)d_ws;
    size_t o = 0;
    auto alloc = [&](size_t bytes) {
        o = (o + 255) & ~(size_t)255;
        void* p = ws + o;
        o += bytes;
        return p;
    };
    int* deg = (int*)alloc(sizeof(int) * NN);
    int* off = (int*)alloc(sizeof(int) * (NN + 1));
    int* cursor = (int*)alloc(sizeof(int) * NN);
    int* csr_dat = (int*)alloc(sizeof(int) * EE);
    __hip_bfloat16* WcatT = (__hip_bfloat16*)alloc(sizeof(__hip_bfloat16) * 128 * KAGG);
    __hip_bfloat16* WgT = (__hip_bfloat16*)alloc(sizeof(__hip_bfloat16) * NGATES * KGATES);
    float* bias512 = (float*)alloc(sizeof(float) * NGATES);
    float* h0 = (float*)alloc(sizeof(float) * (size_t)NN * DD);
    float* h1p = (float*)alloc(sizeof(float) * (size_t)NN * DD);
    float* hini = (float*)alloc(sizeof(float) * (size_t)NN * DD);
    __hip_bfloat16* h_bf = (__hip_bfloat16*)alloc(sizeof(__hip_bfloat16) * (size_t)NN * DD);
    __hip_bfloat16* g = (__hip_bfloat16*)alloc(sizeof(__hip_bfloat16) * (size_t)NN * KAGG);
    __hip_bfloat16* abuf = (__hip_bfloat16*)alloc(sizeof(__hip_bfloat16) * (size_t)NN * DD);
    float* feats = (float*)alloc(sizeof(float) * BB * DD);
    // gates_pre (N x 512 bf16 = 51.2MB) aliases g (54.4MB): g is dead once abuf is computed
    __hip_bfloat16* gates_pre = g;

    // setup
    k_init_h<<<(NN * DD + 255) / 256, 256, 0, stream>>>(features, h0, hini, h_bf);
    k_zero_i32<<<(NN + 255) / 256, 256, 0, stream>>>(deg, NN);
    k_zero_f32<<<(BB * DD + 255) / 256, 256, 0, stream>>>(feats, BB * DD);
    k_hist<<<(EE + 255) / 256, 256, 0, stream>>>(dst, deg);
    k_scan<<<1, 1024, 0, stream>>>(deg, off, cursor);
    k_fill<<<(EE + 255) / 256, 256, 0, stream>>>(dst, src, etype, cursor, csr_dat);
    {
        int prep_n = 128 * KAGG + NGATES * KGATES + NGATES;
        k_prep_w<<<(prep_n + 255) / 256, 256, 0, stream>>>(W_msg, b_msg, w_ih, b_ih, w_hh,
                                                           b_hh, WcatT, WgT, bias512);
    }

    const int MT = (NN + 127) / 128;  // 391 row tiles
    float* hc = h0;
    float* hx = h1p;
    for (int s = 0; s < STEPS; ++s) {
        k_agg<<<(NN * 64 + 255) / 256, 256, 0, stream>>>(h_bf, off, csr_dat, g);
        gemm_mfma<false><<<dim3(MT, 1), 256, 0, stream>>>(g, (const __hip_bfloat16*)nullptr,
                                                          KAGG, KAGG, WcatT, KAGG, nullptr,
                                                          abuf, DD);
        gemm_mfma<true><<<dim3(MT, 4), 256, 0, stream>>>(abuf, h_bf, DD, KGATES, WgT, KGATES,
                                                         bias512, gates_pre, NGATES);
        k_gates<<<(NN * 64 + 255) / 256, 256, 0, stream>>>(gates_pre, hc, hx, h_bf);
        float* tmp = hc;
        hc = hx;
        hx = tmp;
    }
    k_readout<<<(NN + 383) / 384, 128, 0, stream>>>(hc, hini, n2g, feats);
    k_cls<<<1, 128, 0, stream>>>(feats, W_cls, b_cls, out);
}

// Round 3
// 1465.691 us; speedup vs baseline: 2.2651x; 1.0738x over previous
//
#include <hip/hip_runtime.h>
#include <hip/hip_bf16.h>
#include <math.h>

// Problem constants (fixed by the reference)
#define NN 50000
#define EE 400000
#define TT 4
#define DIN 64
#define DD 128
#define BB 64
#define STEPS 8
#define KAGG 544    // 512 (T*D) + 4 (per-type counts for b_msg) + 28 pad -> 17*32
#define KGATES 256  // [a | h]
#define NGATES 512  // [r_sum, z_sum, i_n, h_n]
#define NBIN (4 * NN)  // (dst, etype) bins

typedef __attribute__((ext_vector_type(8))) short bf16x8;
typedef __attribute__((ext_vector_type(4))) float f32x4;
typedef __attribute__((address_space(3))) void lds_void;
typedef __attribute__((address_space(1))) void glob_void;

__device__ inline float bf2f(__hip_bfloat16 x) { return __bfloat162float(x); }

// ---------------------------------------------------------------- init h (zero-pad 64->128)
__global__ void k_init_h(const float* __restrict__ feat, float* __restrict__ h,
                         float* __restrict__ h1, __hip_bfloat16* __restrict__ hb) {
    int idx = blockIdx.x * blockDim.x + threadIdx.x;
    if (idx >= NN * DD) return;
    int v = idx >> 7, d = idx & 127;
    float val = (d < DIN) ? feat[v * DIN + d] : 0.0f;
    h[idx] = val;
    h1[idx] = val;
    hb[idx] = __float2bfloat16(val);
}

__global__ void k_zero_i32(int* __restrict__ p, int n) {
    int idx = blockIdx.x * blockDim.x + threadIdx.x;
    if (idx < n) p[idx] = 0;
}
__global__ void k_zero_f32(float* __restrict__ p, int n) {
    int idx = blockIdx.x * blockDim.x + threadIdx.x;
    if (idx < n) p[idx] = 0.0f;
}

// ---------------------------------------------------------------- CSR build by (dst,type)
__global__ void k_hist(const int* __restrict__ dst, const int* __restrict__ etype,
                       int* __restrict__ deg2) {
    int e = blockIdx.x * blockDim.x + threadIdx.x;
    if (e < EE) atomicAdd(&deg2[dst[e] * 4 + etype[e]], 1);
}

__global__ __launch_bounds__(1024) void k_scan(const int* __restrict__ deg2,
                                               int* __restrict__ off2,
                                               int* __restrict__ cursor) {
    __shared__ int sums[1024];
    int tid = threadIdx.x;
    const int CH = (NBIN + 1023) / 1024;  // 196
    int start = tid * CH;
    int end = start + CH;
    if (start > NBIN) start = NBIN;
    if (end > NBIN) end = NBIN;
    int s = 0;
    for (int i = start; i < end; ++i) s += deg2[i];
    sums[tid] = s;
    __syncthreads();
    for (int dlt = 1; dlt < 1024; dlt <<= 1) {
        int v = (tid >= dlt) ? sums[tid - dlt] : 0;
        __syncthreads();
        sums[tid] += v;
        __syncthreads();
    }
    int run = sums[tid] - s;  // exclusive base
    for (int i = start; i < end; ++i) {
        off2[i] = run;
        cursor[i] = run;
        run += deg2[i];
    }
    if (end == NBIN && start < NBIN) off2[NBIN] = run;  // == EE
}

__global__ void k_fill(const int* __restrict__ dst, const int* __restrict__ src,
                       const int* __restrict__ etype, int* __restrict__ cursor,
                       int* __restrict__ csr_src) {
    int e = blockIdx.x * blockDim.x + threadIdx.x;
    if (e < EE) {
        int pos = atomicAdd(&cursor[dst[e] * 4 + etype[e]], 1);
        csr_src[pos] = src[e];
    }
}

// counts columns of g (cols 512..543) are constant across steps: write once
__global__ void k_counts(const int* __restrict__ off2, __hip_bfloat16* __restrict__ g) {
    int idx = blockIdx.x * blockDim.x + threadIdx.x;
    if (idx >= NN * 16) return;
    int v = idx >> 4, j = idx & 15;
    float x = 0.0f, y = 0.0f;
    if (j < 2) {
        int t0 = 2 * j;
        x = (float)(off2[4 * v + t0 + 1] - off2[4 * v + t0]);
        y = (float)(off2[4 * v + t0 + 2] - off2[4 * v + t0 + 1]);
    }
    __hip_bfloat162 o;
    o.x = __float2bfloat16(x);
    o.y = __float2bfloat16(y);
    ((__hip_bfloat162*)(g + (size_t)v * KAGG))[256 + j] = o;
}

// ---------------------------------------------------------------- weight prep (once/call)
__global__ void k_prep_w(const float* __restrict__ Wm, const float* __restrict__ bm,
                         const float* __restrict__ wih, const float* __restrict__ bih,
                         const float* __restrict__ whh, const float* __restrict__ bhh,
                         __hip_bfloat16* __restrict__ WcatT, __hip_bfloat16* __restrict__ WgT,
                         float* __restrict__ bias512) {
    int idx = blockIdx.x * blockDim.x + threadIdx.x;
    if (idx < 128 * KAGG) {
        int n = idx / KAGG, k = idx % KAGG;
        float v = 0.0f;
        if (k < 512) {
            int t = k >> 7, d = k & 127;
            v = Wm[(t << 14) + (d << 7) + n];
        } else if (k < 516) {
            v = bm[((k - 512) << 7) + n];
        }
        WcatT[idx] = __float2bfloat16(v);
    }
    int j = idx - 128 * KAGG;
    if (j >= 0 && j < NGATES * KGATES) {
        int n = j >> 8, k = j & 255;
        float v;
        if (k < 128) {
            v = (n < 384) ? wih[k * 384 + n] : 0.0f;
        } else {
            int d = k - 128;
            v = (n < 256) ? whh[d * 384 + n] : ((n < 384) ? 0.0f : whh[d * 384 + n - 128]);
        }
        WgT[j] = __float2bfloat16(v);
    }
    int b = idx - (128 * KAGG + NGATES * KGATES);
    if (b >= 0 && b < NGATES) {
        float v;
        if (b < 256) v = bih[b] + bhh[b];
        else if (b < 384) v = bih[b];
        else v = bhh[b - 128];
        bias512[b] = v;
    }
}

// ---------------------------------------------------------------- per-type aggregation
// one wave per node; lane owns dims (2*lane, 2*lane+1); type-sorted CSR -> no masking
__global__ __launch_bounds__(256) void k_agg(const __hip_bfloat16* __restrict__ hb,
                                             const int* __restrict__ off2,
                                             const int* __restrict__ csr_src,
                                             __hip_bfloat16* __restrict__ g) {
    int node = (blockIdx.x * blockDim.x + threadIdx.x) >> 6;
    int lane = threadIdx.x & 63;
    if (node >= NN) return;
    const __hip_bfloat162* hb2 = (const __hip_bfloat162*)hb;
    __hip_bfloat162* grow = (__hip_bfloat162*)(g + (size_t)node * KAGG);
    int b0 = off2[4 * node];
    int b1 = off2[4 * node + 1];
    int b2 = off2[4 * node + 2];
    int b3 = off2[4 * node + 3];
    int b4 = off2[4 * node + 4];
    int beg[5] = {b0, b1, b2, b3, b4};
#pragma unroll
    for (int t = 0; t < TT; ++t) {
        float ax = 0.0f, ay = 0.0f;
        int p = beg[t], e = beg[t + 1];
        for (; p + 1 < e; p += 2) {  // 2-way unroll for load-latency overlap
            int s0 = csr_src[p];
            int s1 = csr_src[p + 1];
            __hip_bfloat162 v0 = hb2[(size_t)s0 * 64 + lane];
            __hip_bfloat162 v1 = hb2[(size_t)s1 * 64 + lane];
            ax += bf2f(v0.x) + bf2f(v1.x);
            ay += bf2f(v0.y) + bf2f(v1.y);
        }
        if (p < e) {
            int s0 = csr_src[p];
            __hip_bfloat162 v0 = hb2[(size_t)s0 * 64 + lane];
            ax += bf2f(v0.x);
            ay += bf2f(v0.y);
        }
        __hip_bfloat162 o;
        o.x = __float2bfloat16(ax);
        o.y = __float2bfloat16(ay);
        grow[t * 64 + lane] = o;
    }
}

// ---------------------------------------------------------------- MFMA GEMM (agg transform)
// abuf[N,128] = g[N,544] @ WcatT^T ; 128x128 tile, BK=32, 4 waves 2x2
__global__ __launch_bounds__(256) void gemm_mfma(const __hip_bfloat16* __restrict__ A,
                                                 const __hip_bfloat16* __restrict__ BT,
                                                 __hip_bfloat16* __restrict__ C) {
    __shared__ short As[128 * 32];
    __shared__ short Bs[128 * 32];
    const int tid = threadIdx.x;
    const int lane = tid & 63;
    const int wave = tid >> 6;
    const int row0 = blockIdx.x * 128;
    const int wm = (wave & 1) * 64;
    const int wn = (wave >> 1) * 64;
    const int quad = lane >> 4;
    const int m16 = lane & 15;

    f32x4 acc[4][4];
#pragma unroll
    for (int t = 0; t < 4; ++t)
#pragma unroll
        for (int u = 0; u < 4; ++u) acc[t][u] = (f32x4){0.f, 0.f, 0.f, 0.f};

    for (int k0 = 0; k0 < KAGG; k0 += 32) {
#pragma unroll
        for (int i = 0; i < 2; ++i) {
            int s = tid + i * 256;
            int srow = s >> 2;
            int kp = (s & 3) * 8;
            int grow = row0 + srow;
            if (grow >= NN) grow = NN - 1;
            const __hip_bfloat16* ga = A + (size_t)grow * KAGG + k0 + kp;
            __builtin_amdgcn_global_load_lds((const glob_void*)ga,
                                             (lds_void*)&As[(wave * 64 + i * 256) * 8], 16, 0, 0);
            const __hip_bfloat16* gb = BT + (size_t)srow * KAGG + k0 + kp;
            __builtin_amdgcn_global_load_lds((const glob_void*)gb,
                                             (lds_void*)&Bs[(wave * 64 + i * 256) * 8], 16, 0, 0);
        }
        __syncthreads();
        bf16x8 af[4], bfr[4];
#pragma unroll
        for (int t = 0; t < 4; ++t) af[t] = *(bf16x8*)&As[(wm + t * 16 + m16) * 32 + quad * 8];
#pragma unroll
        for (int u = 0; u < 4; ++u) bfr[u] = *(bf16x8*)&Bs[(wn + u * 16 + m16) * 32 + quad * 8];
#pragma unroll
        for (int t = 0; t < 4; ++t)
#pragma unroll
            for (int u = 0; u < 4; ++u)
                acc[t][u] = __builtin_amdgcn_mfma_f32_16x16x32_bf16(af[t], bfr[u], acc[t][u], 0, 0, 0);
        __syncthreads();
    }
#pragma unroll
    for (int u = 0; u < 4; ++u) {
        int col = wn + u * 16 + m16;
#pragma unroll
        for (int t = 0; t < 4; ++t) {
            int rbase = row0 + wm + t * 16 + quad * 4;
#pragma unroll
            for (int r = 0; r < 4; ++r) {
                int row = rbase + r;
                if (row < NN) C[(size_t)row * DD + col] = __float2bfloat16(acc[t][u][r]);
            }
        }
    }
}

// ---------------------------------------------------------------- fused gates GEMM + GRU
// Tile: 128 rows x (4 gate groups x 32 d-cols). Wave w owns rows [w*32, w*32+32).
// Each wave computes all 4 gate groups for its 32-d slice -> GRU fuses in-register.
__global__ __launch_bounds__(256) void gemm_gru(const __hip_bfloat16* __restrict__ A0,  // abuf
                                                const __hip_bfloat16* __restrict__ A1,  // h_bf
                                                const __hip_bfloat16* __restrict__ WgT,
                                                const float* __restrict__ bias512,
                                                const float* __restrict__ hp,   // h fp32 in
                                                float* __restrict__ ho,         // h fp32 out
                                                __hip_bfloat16* __restrict__ hbo) {
    __shared__ short As[128 * 32];
    __shared__ short Bs[128 * 32];
    const int tid = threadIdx.x;
    const int lane = tid & 63;
    const int wave = tid >> 6;
    const int row0 = blockIdx.x * 128;
    const int cy = blockIdx.y;  // d-slice [cy*32, cy*32+32)
    const int quad = lane >> 4;
    const int m16 = lane & 15;

    f32x4 acc[2][4][2];  // [row-tile][gate][col-tile]
#pragma unroll
    for (int t = 0; t < 2; ++t)
#pragma unroll
        for (int gg = 0; gg < 4; ++gg)
#pragma unroll
            for (int c = 0; c < 2; ++c) acc[t][gg][c] = (f32x4){0.f, 0.f, 0.f, 0.f};

    for (int k0 = 0; k0 < KGATES; k0 += 32) {
#pragma unroll
        for (int i = 0; i < 2; ++i) {
            int s = tid + i * 256;
            int srow = s >> 2;
            int kp = (s & 3) * 8;
            int grow = row0 + srow;
            if (grow >= NN) grow = NN - 1;
            const __hip_bfloat16* ga = (k0 < 128) ? A0 + (size_t)grow * DD + k0 + kp
                                                  : A1 + (size_t)grow * DD + (k0 - 128) + kp;
            __builtin_amdgcn_global_load_lds((const glob_void*)ga,
                                             (lds_void*)&As[(wave * 64 + i * 256) * 8], 16, 0, 0);
            int bcol = ((srow >> 5) << 7) + cy * 32 + (srow & 31);  // gate group + d
            const __hip_bfloat16* gb = WgT + (size_t)bcol * KGATES + k0 + kp;
            __builtin_amdgcn_global_load_lds((const glob_void*)gb,
                                             (lds_void*)&Bs[(wave * 64 + i * 256) * 8], 16, 0, 0);
        }
        __syncthreads();
        bf16x8 af[2], bfr[4][2];
#pragma unroll
        for (int t = 0; t < 2; ++t)
            af[t] = *(bf16x8*)&As[(wave * 32 + t * 16 + m16) * 32 + quad * 8];
#pragma unroll
        for (int gg = 0; gg < 4; ++gg)
#pragma unroll
            for (int c = 0; c < 2; ++c)
                bfr[gg][c] = *(bf16x8*)&Bs[((gg << 5) + c * 16 + m16) * 32 + quad * 8];
#pragma unroll
        for (int t = 0; t < 2; ++t)
#pragma unroll
            for (int gg = 0; gg < 4; ++gg)
#pragma unroll
                for (int c = 0; c < 2; ++c)
                    acc[t][gg][c] =
                        __builtin_amdgcn_mfma_f32_16x16x32_bf16(af[t], bfr[gg][c], acc[t][gg][c], 0, 0, 0);
        __syncthreads();
    }
    // Epilogue: in-register GRU. Identical C/D layout across gate groups.
#pragma unroll
    for (int c = 0; c < 2; ++c) {
        int d = cy * 32 + c * 16 + m16;
        float brs = bias512[d];
        float bzs = bias512[128 + d];
        float bin_ = bias512[256 + d];
        float bhn = bias512[384 + d];
#pragma unroll
        for (int t = 0; t < 2; ++t) {
            int rbase = row0 + wave * 32 + t * 16 + quad * 4;
#pragma unroll
            for (int r = 0; r < 4; ++r) {
                int row = rbase + r;
                if (row >= NN) continue;
                float rs = acc[t][0][c][r] + brs;
                float zs = acc[t][1][c][r] + bzs;
                float inn = acc[t][2][c][r] + bin_;
                float hnn = acc[t][3][c][r] + bhn;
                float rr = 1.0f / (1.0f + __expf(-rs));
                float zz = 1.0f / (1.0f + __expf(-zs));
                float ng = tanhf(inn + rr * hnn);
                float hv = hp[(size_t)row * DD + d];
                float o = (1.0f - zz) * ng + zz * hv;
                ho[(size_t)row * DD + d] = o;
                hbo[(size_t)row * DD + d] = __float2bfloat16(o);
            }
        }
    }
}

// ---------------------------------------------------------------- readout (n2g is sorted)
__global__ __launch_bounds__(128) void k_readout(const float* __restrict__ h,
                                                 const float* __restrict__ h1,
                                                 const int* __restrict__ n2g,
                                                 float* __restrict__ feats) {
    const int CHN = 64;
    int d = threadIdx.x;
    int v0 = blockIdx.x * CHN;
    if (v0 >= NN) return;
    int v1 = v0 + CHN;
    if (v1 > NN) v1 = NN;
    float sum = 0.0f;
    int cur = n2g[v0];
    for (int v = v0; v < v1; ++v) {
        int gph = n2g[v];
        if (gph != cur) {
            atomicAdd(&feats[cur * DD + d], sum);
            sum = 0.0f;
            cur = gph;
        }
        sum += h[(size_t)v * DD + d] + h1[(size_t)v * DD + d];
    }
    atomicAdd(&feats[cur * DD + d], sum);
}

// ---------------------------------------------------------------- classifier
__global__ void k_cls(const float* __restrict__ feats, const float* __restrict__ Wc,
                      const float* __restrict__ bc, float* __restrict__ out) {
    int t = threadIdx.x;
    if (t >= BB * 2) return;
    int b = t >> 1, c = t & 1;
    float s = bc[c];
    for (int d = 0; d < DD; ++d) s += feats[b * DD + d] * Wc[d * 2 + c];
    out[t] = s;
}

// ================================================================ launcher
extern "C" void kernel_launch(void* const* d_in, const int* in_sizes, int n_in, void* d_out,
                              int out_size, void* d_ws, size_t ws_size, hipStream_t stream) {
    const float* features = (const float*)d_in[0];
    const int* src = (const int*)d_in[1];
    const int* dst = (const int*)d_in[2];
    const int* etype = (const int*)d_in[3];
    const int* n2g = (const int*)d_in[4];
    const float* W_msg = (const float*)d_in[5];
    const float* b_msg = (const float*)d_in[6];
    const float* w_ih = (const float*)d_in[7];
    const float* b_ih = (const float*)d_in[8];
    const float* w_hh = (const float*)d_in[9];
    const float* b_hh = (const float*)d_in[10];
    const float* W_cls = (const float*)d_in[11];
    const float* b_cls = (const float*)d_in[12];
    float* out = (float*)d_out;

    char* ws = (char*)d_ws;
    size_t o = 0;
    auto alloc = [&](size_t bytes) {
        o = (o + 255) & ~(size_t)255;
        void* p = ws + o;
        o += bytes;
        return p;
    };
    int* deg2 = (int*)alloc(sizeof(int) * NBIN);
    int* off2 = (int*)alloc(sizeof(int) * (NBIN + 1));
    int* cursor = (int*)alloc(sizeof(int) * NBIN);
    int* csr_src = (int*)alloc(sizeof(int) * EE);
    __hip_bfloat16* WcatT = (__hip_bfloat16*)alloc(sizeof(__hip_bfloat16) * 128 * KAGG);
    __hip_bfloat16* WgT = (__hip_bfloat16*)alloc(sizeof(__hip_bfloat16) * NGATES * KGATES);
    float* bias512 = (float*)alloc(sizeof(float) * NGATES);
    float* h0 = (float*)alloc(sizeof(float) * (size_t)NN * DD);
    float* h1p = (float*)alloc(sizeof(float) * (size_t)NN * DD);
    float* hini = (float*)alloc(sizeof(float) * (size_t)NN * DD);
    __hip_bfloat16* hbfA = (__hip_bfloat16*)alloc(sizeof(__hip_bfloat16) * (size_t)NN * DD);
    __hip_bfloat16* hbfB = (__hip_bfloat16*)alloc(sizeof(__hip_bfloat16) * (size_t)NN * DD);
    __hip_bfloat16* g = (__hip_bfloat16*)alloc(sizeof(__hip_bfloat16) * (size_t)NN * KAGG);
    __hip_bfloat16* abuf = (__hip_bfloat16*)alloc(sizeof(__hip_bfloat16) * (size_t)NN * DD);
    float* feats = (float*)alloc(sizeof(float) * BB * DD);

    // setup
    k_init_h<<<(NN * DD + 255) / 256, 256, 0, stream>>>(features, h0, hini, hbfA);
    k_zero_i32<<<(NBIN + 255) / 256, 256, 0, stream>>>(deg2, NBIN);
    k_zero_f32<<<(BB * DD + 255) / 256, 256, 0, stream>>>(feats, BB * DD);
    k_hist<<<(EE + 255) / 256, 256, 0, stream>>>(dst, etype, deg2);
    k_scan<<<1, 1024, 0, stream>>>(deg2, off2, cursor);
    k_fill<<<(EE + 255) / 256, 256, 0, stream>>>(dst, src, etype, cursor, csr_src);
    k_counts<<<(NN * 16 + 255) / 256, 256, 0, stream>>>(off2, g);
    {
        int prep_n = 128 * KAGG + NGATES * KGATES + NGATES;
        k_prep_w<<<(prep_n + 255) / 256, 256, 0, stream>>>(W_msg, b_msg, w_ih, b_ih, w_hh,
                                                           b_hh, WcatT, WgT, bias512);
    }

    const int MT = (NN + 127) / 128;  // 391 row tiles
    float* hc = h0;
    float* hx = h1p;
    __hip_bfloat16* hbc = hbfA;
    __hip_bfloat16* hbx = hbfB;
    for (int s = 0; s < STEPS; ++s) {
        k_agg<<<(NN * 64 + 255) / 256, 256, 0, stream>>>(hbc, off2, csr_src, g);
        gemm_mfma<<<dim3(MT, 1), 256, 0, stream>>>(g, WcatT, abuf);
        gemm_gru<<<dim3(MT, 4), 256, 0, stream>>>(abuf, hbc, WgT, bias512, hc, hx, hbx);
        float* tf = hc; hc = hx; hx = tf;
        __hip_bfloat16* tb = hbc; hbc = hbx; hbx = tb;
    }
    k_readout<<<(NN + 63) / 64, 128, 0, stream>>>(hc, hini, n2g, feats);
    k_cls<<<1, 128, 0, stream>>>(feats, W_cls, b_cls, out);
}

// Round 4
// 1034.187 us; speedup vs baseline: 3.2102x; 1.4172x over previous
//
#include <hip/hip_runtime.h>
#include <hip/hip_bf16.h>
#include <math.h>

// Problem constants (fixed by the reference)
#define NN 50000
#define EE 400000
#define TT 4
#define DIN 64
#define DD 128
#define BB 64
#define STEPS 8
#define KAGG 544    // 512 (T*D) + 4 (per-type counts for b_msg) + 28 pad -> 17*32
#define KGATES 256  // [a | h]
#define NGATES 512  // [r_sum, z_sum, i_n, h_n]
#define NBIN (4 * NN)             // (dst, etype) bins
#define NBLK ((NBIN + 255) / 256) // 782 scan blocks

typedef __attribute__((ext_vector_type(8))) short bf16x8;
typedef __attribute__((ext_vector_type(4))) float f32x4;
typedef __attribute__((address_space(3))) void lds_void;
typedef __attribute__((address_space(1))) void glob_void;

__device__ inline float bf2f(__hip_bfloat16 x) { return __bfloat162float(x); }

// ---------------------------------------------------------------- init h (zero-pad 64->128)
__global__ void k_init_h(const float* __restrict__ feat, float* __restrict__ h,
                         float* __restrict__ h1, __hip_bfloat16* __restrict__ hb) {
    int idx = blockIdx.x * blockDim.x + threadIdx.x;
    if (idx >= NN * DD) return;
    int v = idx >> 7, d = idx & 127;
    float val = (d < DIN) ? feat[v * DIN + d] : 0.0f;
    h[idx] = val;
    h1[idx] = val;
    hb[idx] = __float2bfloat16(val);
}

__global__ void k_zero_i32(int* __restrict__ p, int n) {
    int idx = blockIdx.x * blockDim.x + threadIdx.x;
    if (idx < n) p[idx] = 0;
}
__global__ void k_zero_f32(float* __restrict__ p, int n) {
    int idx = blockIdx.x * blockDim.x + threadIdx.x;
    if (idx < n) p[idx] = 0.0f;
}

// ---------------------------------------------------------------- CSR build by (dst,type)
__global__ void k_hist(const int* __restrict__ dst, const int* __restrict__ etype,
                       int* __restrict__ deg2) {
    int e = blockIdx.x * blockDim.x + threadIdx.x;
    if (e < EE) atomicAdd(&deg2[dst[e] * 4 + etype[e]], 1);
}

// ---- 3-pass device-wide exclusive scan over deg2[NBIN] ----
__global__ __launch_bounds__(256) void k_scan_bsum(const int* __restrict__ deg2,
                                                   int* __restrict__ bsum) {
    __shared__ int red[256];
    int tid = threadIdx.x;
    int i = blockIdx.x * 256 + tid;
    int v = (i < NBIN) ? deg2[i] : 0;
    red[tid] = v;
    __syncthreads();
#pragma unroll
    for (int s = 128; s > 0; s >>= 1) {
        if (tid < s) red[tid] += red[tid + s];
        __syncthreads();
    }
    if (tid == 0) bsum[blockIdx.x] = red[0];
}

__global__ __launch_bounds__(1024) void k_scan_boff(const int* __restrict__ bsum,
                                                    int* __restrict__ boff) {
    __shared__ int s[1024];
    int tid = threadIdx.x;
    int v = (tid < NBLK) ? bsum[tid] : 0;
    s[tid] = v;
    __syncthreads();
    for (int d = 1; d < 1024; d <<= 1) {
        int t = (tid >= d) ? s[tid - d] : 0;
        __syncthreads();
        s[tid] += t;
        __syncthreads();
    }
    if (tid < NBLK) boff[tid] = s[tid] - v;  // exclusive
}

__global__ __launch_bounds__(256) void k_scan_final(const int* __restrict__ deg2,
                                                    const int* __restrict__ boff,
                                                    int* __restrict__ off2,
                                                    int* __restrict__ cursor) {
    __shared__ int s[256];
    int tid = threadIdx.x;
    int i = blockIdx.x * 256 + tid;
    int v = (i < NBIN) ? deg2[i] : 0;
    s[tid] = v;
    __syncthreads();
#pragma unroll
    for (int d = 1; d < 256; d <<= 1) {
        int t = (tid >= d) ? s[tid - d] : 0;
        __syncthreads();
        s[tid] += t;
        __syncthreads();
    }
    int excl = boff[blockIdx.x] + s[tid] - v;
    if (i < NBIN) {
        off2[i] = excl;
        cursor[i] = excl;
        if (i == NBIN - 1) off2[NBIN] = excl + v;  // == EE
    }
}

__global__ void k_fill(const int* __restrict__ dst, const int* __restrict__ src,
                       const int* __restrict__ etype, int* __restrict__ cursor,
                       int* __restrict__ csr_src) {
    int e = blockIdx.x * blockDim.x + threadIdx.x;
    if (e < EE) {
        int pos = atomicAdd(&cursor[dst[e] * 4 + etype[e]], 1);
        csr_src[pos] = src[e];
    }
}

// counts columns of g (cols 512..543) are constant across steps: write once
__global__ void k_counts(const int* __restrict__ off2, __hip_bfloat16* __restrict__ g) {
    int idx = blockIdx.x * blockDim.x + threadIdx.x;
    if (idx >= NN * 16) return;
    int v = idx >> 4, j = idx & 15;
    float x = 0.0f, y = 0.0f;
    if (j < 2) {
        int t0 = 2 * j;
        x = (float)(off2[4 * v + t0 + 1] - off2[4 * v + t0]);
        y = (float)(off2[4 * v + t0 + 2] - off2[4 * v + t0 + 1]);
    }
    __hip_bfloat162 o;
    o.x = __float2bfloat16(x);
    o.y = __float2bfloat16(y);
    ((__hip_bfloat162*)(g + (size_t)v * KAGG))[256 + j] = o;
}

// ---------------------------------------------------------------- weight prep (once/call)
__global__ void k_prep_w(const float* __restrict__ Wm, const float* __restrict__ bm,
                         const float* __restrict__ wih, const float* __restrict__ bih,
                         const float* __restrict__ whh, const float* __restrict__ bhh,
                         __hip_bfloat16* __restrict__ WcatT, __hip_bfloat16* __restrict__ WgT,
                         float* __restrict__ bias512) {
    int idx = blockIdx.x * blockDim.x + threadIdx.x;
    if (idx < 128 * KAGG) {
        int n = idx / KAGG, k = idx % KAGG;
        float v = 0.0f;
        if (k < 512) {
            int t = k >> 7, d = k & 127;
            v = Wm[(t << 14) + (d << 7) + n];
        } else if (k < 516) {
            v = bm[((k - 512) << 7) + n];
        }
        WcatT[idx] = __float2bfloat16(v);
    }
    int j = idx - 128 * KAGG;
    if (j >= 0 && j < NGATES * KGATES) {
        int n = j >> 8, k = j & 255;
        float v;
        if (k < 128) {
            v = (n < 384) ? wih[k * 384 + n] : 0.0f;
        } else {
            int d = k - 128;
            v = (n < 256) ? whh[d * 384 + n] : ((n < 384) ? 0.0f : whh[d * 384 + n - 128]);
        }
        WgT[j] = __float2bfloat16(v);
    }
    int b = idx - (128 * KAGG + NGATES * KGATES);
    if (b >= 0 && b < NGATES) {
        float v;
        if (b < 256) v = bih[b] + bhh[b];
        else if (b < 384) v = bih[b];
        else v = bhh[b - 128];
        bias512[b] = v;
    }
}

// ---------------------------------------------------------------- per-type aggregation
// one wave per node; lane owns dims (2*lane, 2*lane+1); type-sorted CSR -> no masking
__global__ __launch_bounds__(256) void k_agg(const __hip_bfloat16* __restrict__ hb,
                                             const int* __restrict__ off2,
                                             const int* __restrict__ csr_src,
                                             __hip_bfloat16* __restrict__ g) {
    int node = (blockIdx.x * blockDim.x + threadIdx.x) >> 6;
    int lane = threadIdx.x & 63;
    if (node >= NN) return;
    const __hip_bfloat162* hb2 = (const __hip_bfloat162*)hb;
    __hip_bfloat162* grow = (__hip_bfloat162*)(g + (size_t)node * KAGG);
    int b0 = off2[4 * node];
    int b1 = off2[4 * node + 1];
    int b2 = off2[4 * node + 2];
    int b3 = off2[4 * node + 3];
    int b4 = off2[4 * node + 4];
    int beg[5] = {b0, b1, b2, b3, b4};
#pragma unroll
    for (int t = 0; t < TT; ++t) {
        float ax = 0.0f, ay = 0.0f;
        int p = beg[t], e = beg[t + 1];
        for (; p + 1 < e; p += 2) {  // 2-way unroll for load-latency overlap
            int s0 = csr_src[p];
            int s1 = csr_src[p + 1];
            __hip_bfloat162 v0 = hb2[(size_t)s0 * 64 + lane];
            __hip_bfloat162 v1 = hb2[(size_t)s1 * 64 + lane];
            ax += bf2f(v0.x) + bf2f(v1.x);
            ay += bf2f(v0.y) + bf2f(v1.y);
        }
        if (p < e) {
            int s0 = csr_src[p];
            __hip_bfloat162 v0 = hb2[(size_t)s0 * 64 + lane];
            ax += bf2f(v0.x);
            ay += bf2f(v0.y);
        }
        __hip_bfloat162 o;
        o.x = __float2bfloat16(ax);
        o.y = __float2bfloat16(ay);
        grow[t * 64 + lane] = o;
    }
}

// ---------------------------------------------------------------- MFMA GEMM (agg transform)
// abuf[N,128] = g[N,544] @ WcatT^T ; 128x128 tile, BK=32, 4 waves 2x2
__global__ __launch_bounds__(256) void gemm_mfma(const __hip_bfloat16* __restrict__ A,
                                                 const __hip_bfloat16* __restrict__ BT,
                                                 __hip_bfloat16* __restrict__ C) {
    __shared__ short As[128 * 32];
    __shared__ short Bs[128 * 32];
    const int tid = threadIdx.x;
    const int lane = tid & 63;
    const int wave = tid >> 6;
    const int row0 = blockIdx.x * 128;
    const int wm = (wave & 1) * 64;
    const int wn = (wave >> 1) * 64;
    const int quad = lane >> 4;
    const int m16 = lane & 15;

    f32x4 acc[4][4];
#pragma unroll
    for (int t = 0; t < 4; ++t)
#pragma unroll
        for (int u = 0; u < 4; ++u) acc[t][u] = (f32x4){0.f, 0.f, 0.f, 0.f};

    for (int k0 = 0; k0 < KAGG; k0 += 32) {
#pragma unroll
        for (int i = 0; i < 2; ++i) {
            int s = tid + i * 256;
            int srow = s >> 2;
            int kp = (s & 3) * 8;
            int grow = row0 + srow;
            if (grow >= NN) grow = NN - 1;
            const __hip_bfloat16* ga = A + (size_t)grow * KAGG + k0 + kp;
            __builtin_amdgcn_global_load_lds((const glob_void*)ga,
                                             (lds_void*)&As[(wave * 64 + i * 256) * 8], 16, 0, 0);
            const __hip_bfloat16* gb = BT + (size_t)srow * KAGG + k0 + kp;
            __builtin_amdgcn_global_load_lds((const glob_void*)gb,
                                             (lds_void*)&Bs[(wave * 64 + i * 256) * 8], 16, 0, 0);
        }
        __syncthreads();
        bf16x8 af[4], bfr[4];
#pragma unroll
        for (int t = 0; t < 4; ++t) af[t] = *(bf16x8*)&As[(wm + t * 16 + m16) * 32 + quad * 8];
#pragma unroll
        for (int u = 0; u < 4; ++u) bfr[u] = *(bf16x8*)&Bs[(wn + u * 16 + m16) * 32 + quad * 8];
#pragma unroll
        for (int t = 0; t < 4; ++t)
#pragma unroll
            for (int u = 0; u < 4; ++u)
                acc[t][u] = __builtin_amdgcn_mfma_f32_16x16x32_bf16(af[t], bfr[u], acc[t][u], 0, 0, 0);
        __syncthreads();
    }
#pragma unroll
    for (int u = 0; u < 4; ++u) {
        int col = wn + u * 16 + m16;
#pragma unroll
        for (int t = 0; t < 4; ++t) {
            int rbase = row0 + wm + t * 16 + quad * 4;
#pragma unroll
            for (int r = 0; r < 4; ++r) {
                int row = rbase + r;
                if (row < NN) C[(size_t)row * DD + col] = __float2bfloat16(acc[t][u][r]);
            }
        }
    }
}

// ---------------------------------------------------------------- fused gates GEMM + GRU
// Tile: 128 rows x (4 gate groups x 32 d-cols). Wave w owns rows [w*32, w*32+32).
// Each wave computes all 4 gate groups for its 32-d slice -> GRU fuses in-register.
__global__ __launch_bounds__(256) void gemm_gru(const __hip_bfloat16* __restrict__ A0,  // abuf
                                                const __hip_bfloat16* __restrict__ A1,  // h_bf
                                                const __hip_bfloat16* __restrict__ WgT,
                                                const float* __restrict__ bias512,
                                                const float* __restrict__ hp,   // h fp32 in
                                                float* __restrict__ ho,         // h fp32 out
                                                __hip_bfloat16* __restrict__ hbo) {
    __shared__ short As[128 * 32];
    __shared__ short Bs[128 * 32];
    const int tid = threadIdx.x;
    const int lane = tid & 63;
    const int wave = tid >> 6;
    const int row0 = blockIdx.x * 128;
    const int cy = blockIdx.y;  // d-slice [cy*32, cy*32+32)
    const int quad = lane >> 4;
    const int m16 = lane & 15;

    f32x4 acc[2][4][2];  // [row-tile][gate][col-tile]
#pragma unroll
    for (int t = 0; t < 2; ++t)
#pragma unroll
        for (int gg = 0; gg < 4; ++gg)
#pragma unroll
            for (int c = 0; c < 2; ++c) acc[t][gg][c] = (f32x4){0.f, 0.f, 0.f, 0.f};

    for (int k0 = 0; k0 < KGATES; k0 += 32) {
#pragma unroll
        for (int i = 0; i < 2; ++i) {
            int s = tid + i * 256;
            int srow = s >> 2;
            int kp = (s & 3) * 8;
            int grow = row0 + srow;
            if (grow >= NN) grow = NN - 1;
            const __hip_bfloat16* ga = (k0 < 128) ? A0 + (size_t)grow * DD + k0 + kp
                                                  : A1 + (size_t)grow * DD + (k0 - 128) + kp;
            __builtin_amdgcn_global_load_lds((const glob_void*)ga,
                                             (lds_void*)&As[(wave * 64 + i * 256) * 8], 16, 0, 0);
            int bcol = ((srow >> 5) << 7) + cy * 32 + (srow & 31);  // gate group + d
            const __hip_bfloat16* gb = WgT + (size_t)bcol * KGATES + k0 + kp;
            __builtin_amdgcn_global_load_lds((const glob_void*)gb,
                                             (lds_void*)&Bs[(wave * 64 + i * 256) * 8], 16, 0, 0);
        }
        __syncthreads();
        bf16x8 af[2], bfr[4][2];
#pragma unroll
        for (int t = 0; t < 2; ++t)
            af[t] = *(bf16x8*)&As[(wave * 32 + t * 16 + m16) * 32 + quad * 8];
#pragma unroll
        for (int gg = 0; gg < 4; ++gg)
#pragma unroll
            for (int c = 0; c < 2; ++c)
                bfr[gg][c] = *(bf16x8*)&Bs[((gg << 5) + c * 16 + m16) * 32 + quad * 8];
#pragma unroll
        for (int t = 0; t < 2; ++t)
#pragma unroll
            for (int gg = 0; gg < 4; ++gg)
#pragma unroll
                for (int c = 0; c < 2; ++c)
                    acc[t][gg][c] =
                        __builtin_amdgcn_mfma_f32_16x16x32_bf16(af[t], bfr[gg][c], acc[t][gg][c], 0, 0, 0);
        __syncthreads();
    }
    // Epilogue: in-register GRU. Identical C/D layout across gate groups.
#pragma unroll
    for (int c = 0; c < 2; ++c) {
        int d = cy * 32 + c * 16 + m16;
        float brs = bias512[d];
        float bzs = bias512[128 + d];
        float bin_ = bias512[256 + d];
        float bhn = bias512[384 + d];
#pragma unroll
        for (int t = 0; t < 2; ++t) {
            int rbase = row0 + wave * 32 + t * 16 + quad * 4;
#pragma unroll
            for (int r = 0; r < 4; ++r) {
                int row = rbase + r;
                if (row >= NN) continue;
                float rs = acc[t][0][c][r] + brs;
                float zs = acc[t][1][c][r] + bzs;
                float inn = acc[t][2][c][r] + bin_;
                float hnn = acc[t][3][c][r] + bhn;
                float rr = 1.0f / (1.0f + __expf(-rs));
                float zz = 1.0f / (1.0f + __expf(-zs));
                float ng = tanhf(inn + rr * hnn);
                float hv = hp[(size_t)row * DD + d];
                float o = (1.0f - zz) * ng + zz * hv;
                ho[(size_t)row * DD + d] = o;
                hbo[(size_t)row * DD + d] = __float2bfloat16(o);
            }
        }
    }
}

// ---------------------------------------------------------------- readout (n2g is sorted)
__global__ __launch_bounds__(128) void k_readout(const float* __restrict__ h,
                                                 const float* __restrict__ h1,
                                                 const int* __restrict__ n2g,
                                                 float* __restrict__ feats) {
    const int CHN = 64;
    int d = threadIdx.x;
    int v0 = blockIdx.x * CHN;
    if (v0 >= NN) return;
    int v1 = v0 + CHN;
    if (v1 > NN) v1 = NN;
    float sum = 0.0f;
    int cur = n2g[v0];
    for (int v = v0; v < v1; ++v) {
        int gph = n2g[v];
        if (gph != cur) {
            atomicAdd(&feats[cur * DD + d], sum);
            sum = 0.0f;
            cur = gph;
        }
        sum += h[(size_t)v * DD + d] + h1[(size_t)v * DD + d];
    }
    atomicAdd(&feats[cur * DD + d], sum);
}

// ---------------------------------------------------------------- classifier
__global__ void k_cls(const float* __restrict__ feats, const float* __restrict__ Wc,
                      const float* __restrict__ bc, float* __restrict__ out) {
    int t = threadIdx.x;
    if (t >= BB * 2) return;
    int b = t >> 1, c = t & 1;
    float s = bc[c];
    for (int d = 0; d < DD; ++d) s += feats[b * DD + d] * Wc[d * 2 + c];
    out[t] = s;
}

// ================================================================ launcher
extern "C" void kernel_launch(void* const* d_in, const int* in_sizes, int n_in, void* d_out,
                              int out_size, void* d_ws, size_t ws_size, hipStream_t stream) {
    const float* features = (const float*)d_in[0];
    const int* src = (const int*)d_in[1];
    const int* dst = (const int*)d_in[2];
    const int* etype = (const int*)d_in[3];
    const int* n2g = (const int*)d_in[4];
    const float* W_msg = (const float*)d_in[5];
    const float* b_msg = (const float*)d_in[6];
    const float* w_ih = (const float*)d_in[7];
    const float* b_ih = (const float*)d_in[8];
    const float* w_hh = (const float*)d_in[9];
    const float* b_hh = (const float*)d_in[10];
    const float* W_cls = (const float*)d_in[11];
    const float* b_cls = (const float*)d_in[12];
    float* out = (float*)d_out;

    char* ws = (char*)d_ws;
    size_t o = 0;
    auto alloc = [&](size_t bytes) {
        o = (o + 255) & ~(size_t)255;
        void* p = ws + o;
        o += bytes;
        return p;
    };
    int* deg2 = (int*)alloc(sizeof(int) * NBIN);
    int* off2 = (int*)alloc(sizeof(int) * (NBIN + 1));
    int* cursor = (int*)alloc(sizeof(int) * NBIN);
    int* bsum = (int*)alloc(sizeof(int) * NBLK);
    int* boff = (int*)alloc(sizeof(int) * NBLK);
    int* csr_src = (int*)alloc(sizeof(int) * EE);
    __hip_bfloat16* WcatT = (__hip_bfloat16*)alloc(sizeof(__hip_bfloat16) * 128 * KAGG);
    __hip_bfloat16* WgT = (__hip_bfloat16*)alloc(sizeof(__hip_bfloat16) * NGATES * KGATES);
    float* bias512 = (float*)alloc(sizeof(float) * NGATES);
    float* h0 = (float*)alloc(sizeof(float) * (size_t)NN * DD);
    float* h1p = (float*)alloc(sizeof(float) * (size_t)NN * DD);
    float* hini = (float*)alloc(sizeof(float) * (size_t)NN * DD);
    __hip_bfloat16* hbfA = (__hip_bfloat16*)alloc(sizeof(__hip_bfloat16) * (size_t)NN * DD);
    __hip_bfloat16* hbfB = (__hip_bfloat16*)alloc(sizeof(__hip_bfloat16) * (size_t)NN * DD);
    __hip_bfloat16* g = (__hip_bfloat16*)alloc(sizeof(__hip_bfloat16) * (size_t)NN * KAGG);
    __hip_bfloat16* abuf = (__hip_bfloat16*)alloc(sizeof(__hip_bfloat16) * (size_t)NN * DD);
    float* feats = (float*)alloc(sizeof(float) * BB * DD);

    // setup
    k_init_h<<<(NN * DD + 255) / 256, 256, 0, stream>>>(features, h0, hini, hbfA);
    k_zero_i32<<<(NBIN + 255) / 256, 256, 0, stream>>>(deg2, NBIN);
    k_zero_f32<<<(BB * DD + 255) / 256, 256, 0, stream>>>(feats, BB * DD);
    k_hist<<<(EE + 255) / 256, 256, 0, stream>>>(dst, etype, deg2);
    k_scan_bsum<<<NBLK, 256, 0, stream>>>(deg2, bsum);
    k_scan_boff<<<1, 1024, 0, stream>>>(bsum, boff);
    k_scan_final<<<NBLK, 256, 0, stream>>>(deg2, boff, off2, cursor);
    k_fill<<<(EE + 255) / 256, 256, 0, stream>>>(dst, src, etype, cursor, csr_src);
    k_counts<<<(NN * 16 + 255) / 256, 256, 0, stream>>>(off2, g);
    {
        int prep_n = 128 * KAGG + NGATES * KGATES + NGATES;
        k_prep_w<<<(prep_n + 255) / 256, 256, 0, stream>>>(W_msg, b_msg, w_ih, b_ih, w_hh,
                                                           b_hh, WcatT, WgT, bias512);
    }

    const int MT = (NN + 127) / 128;  // 391 row tiles
    float* hc = h0;
    float* hx = h1p;
    __hip_bfloat16* hbc = hbfA;
    __hip_bfloat16* hbx = hbfB;
    for (int s = 0; s < STEPS; ++s) {
        k_agg<<<(NN * 64 + 255) / 256, 256, 0, stream>>>(hbc, off2, csr_src, g);
        gemm_mfma<<<dim3(MT, 1), 256, 0, stream>>>(g, WcatT, abuf);
        gemm_gru<<<dim3(MT, 4), 256, 0, stream>>>(abuf, hbc, WgT, bias512, hc, hx, hbx);
        float* tf = hc; hc = hx; hx = tf;
        __hip_bfloat16* tb = hbc; hbc = hbx; hbx = tb;
    }
    k_readout<<<(NN + 63) / 64, 128, 0, stream>>>(hc, hini, n2g, feats);
    k_cls<<<1, 128, 0, stream>>>(feats, W_cls, b_cls, out);
}